// Round 4
// baseline (147.233 us; speedup 1.0000x reference)
//
#include <hip/hip_runtime.h>

#define N_DIM 4096

// One block (256 threads) per row; row held in registers (4 x float4/thread).
// Loss restructure: sum log1p(-p) over masked elems = -Smask/S + rare exact
// corrections for p > 1e-3 (incl. the argmax, computed cancellation-free).
__global__ __launch_bounds__(256) void minfonce_kernel(
    const float* __restrict__ logits,
    const int*   __restrict__ labels,
    float*       __restrict__ out)
{
    const float SCALE = 7.3890560989306495f;   // e^2 (T = 2.0)
    const int row  = blockIdx.x;
    const int tid  = threadIdx.x;
    const int lane = tid & 63;
    const int wv   = tid >> 6;

    __shared__ float sS[4], sX[4], sM[4], sA[4];

    const float4* rp = reinterpret_cast<const float4*>(logits + (size_t)row * N_DIM);
    const int4*   lp = reinterpret_cast<const int4*>(labels);
    const int     li = labels[row];

    // ---- single full pass: e = exp(scale*x) (no shift needed: |scale*x| < 87),
    //      accumulate S (all), Smask (labels differ), Emax ----
    float4 e[4];
    float s_all = 0.f, s_mask = 0.f, emax = 0.f;
#pragma unroll
    for (int k = 0; k < 4; ++k) {
        const float4 t  = rp[tid + 256 * k];
        const int4   lb = lp[tid + 256 * k];
        float4 ee;
        ee.x = __expf(SCALE * t.x);
        ee.y = __expf(SCALE * t.y);
        ee.z = __expf(SCALE * t.z);
        ee.w = __expf(SCALE * t.w);
        e[k] = ee;
        s_all  += (ee.x + ee.y) + (ee.z + ee.w);
        s_mask += ((lb.x != li ? ee.x : 0.f) + (lb.y != li ? ee.y : 0.f))
                + ((lb.z != li ? ee.z : 0.f) + (lb.w != li ? ee.w : 0.f));
        emax = fmaxf(emax, fmaxf(fmaxf(ee.x, ee.y), fmaxf(ee.z, ee.w)));
    }
#pragma unroll
    for (int off = 1; off < 64; off <<= 1) {
        s_all  += __shfl_xor(s_all, off);
        s_mask += __shfl_xor(s_mask, off);
        emax    = fmaxf(emax, __shfl_xor(emax, off));
    }
    if (lane == 0) { sS[wv] = s_all; sX[wv] = s_mask; sM[wv] = emax; }
    __syncthreads();
    const float S     = (sS[0] + sS[1]) + (sS[2] + sS[3]);
    const float Smask = (sX[0] + sX[1]) + (sX[2] + sX[3]);
    const float Emax  = fmaxf(fmaxf(sM[0], sM[1]), fmaxf(sM[2], sM[3]));
    const float invS  = 1.0f / S;
    const float logS  = __logf(S);
    const float tau   = 1e-3f * S;                       // correction threshold (p > 1e-3)
    // 1 - p_max = (S - Emax)/S, computed without catastrophic cancellation blowup;
    // clamp guards the S==Emax rounding case (error <= ~12/4096 on the loss).
    const float qmax  = fmaxf(S - Emax, S * 1e-12f) * invS;

    float acc = 0.f;

    // ---- rare-correction scan: elements with p > 1e-3 get exact log(1-p) ----
#pragma unroll
    for (int k = 0; k < 4; ++k) {
        const float m4 = fmaxf(fmaxf(e[k].x, e[k].y), fmaxf(e[k].z, e[k].w));
        if (m4 > tau) {                       // rare: ~15-20 hits per row total
            const int g  = tid + 256 * k;
            const int4 lb = lp[g];            // reload inside branch (keeps it a real branch)
            { const float ev = e[k].x;
              if (ev > tau && lb.x != li) {
                  const float p = ev * invS;
                  const float q = (ev == Emax) ? qmax : (1.0f - p);
                  acc += __logf(q) + p; } }   // log1p(-p) exact, minus bulk's -p
            { const float ev = e[k].y;
              if (ev > tau && lb.y != li) {
                  const float p = ev * invS;
                  const float q = (ev == Emax) ? qmax : (1.0f - p);
                  acc += __logf(q) + p; } }
            { const float ev = e[k].z;
              if (ev > tau && lb.z != li) {
                  const float p = ev * invS;
                  const float q = (ev == Emax) ? qmax : (1.0f - p);
                  acc += __logf(q) + p; } }
            { const float ev = e[k].w;
              if (ev > tau && lb.w != li) {
                  const float p = ev * invS;
                  const float q = (ev == Emax) ? qmax : (1.0f - p);
                  acc += __logf(q) + p; } }
        }
    }

    // ---- diagonal term: owning thread picks its register copy ----
    if (tid == ((row >> 2) & 255)) {
        const int k_own = row >> 10;
        const int sub   = row & 3;
        const float4 ek = (k_own == 0) ? e[0] : (k_own == 1) ? e[1]
                        : (k_own == 2) ? e[2] : e[3];
        const float ed  = (sub == 0) ? ek.x : (sub == 1) ? ek.y
                        : (sub == 2) ? ek.z : ek.w;
        // log p_ii = log(e_d) - log(S); e_d is always normal-range (|u|<87)
        acc += __logf(ed) - logS;
    }

#pragma unroll
    for (int off = 1; off < 64; off <<= 1)
        acc += __shfl_xor(acc, off);
    if (lane == 0) sA[wv] = acc;
    __syncthreads();
    if (tid == 0) {
        const float total = (sA[0] + sA[1]) + (sA[2] + sA[3]) - Smask * invS;
        atomicAdd(out, total * (1.0f / N_DIM));
    }
}

extern "C" void kernel_launch(void* const* d_in, const int* in_sizes, int n_in,
                              void* d_out, int out_size, void* d_ws, size_t ws_size,
                              hipStream_t stream) {
    const float* logits = (const float*)d_in[0];
    const int*   labels = (const int*)d_in[1];
    float*       out    = (float*)d_out;

    // d_out is poisoned (0xAA) before every timed launch — zero it ourselves.
    hipMemsetAsync(out, 0, sizeof(float), stream);
    minfonce_kernel<<<N_DIM, 256, 0, stream>>>(logits, labels, out);
}

// Round 5
// 138.107 us; speedup vs baseline: 1.0661x; 1.0661x over previous
//
#include <hip/hip_runtime.h>

#define N_DIM 4096

// One block (256 threads) per row. Single streaming pass, nothing row-sized
// kept live (no spill): pass 1 accumulates S, Smask, per-k-group max only;
// the rare-correction scan re-loads from L1/L2 and recomputes exp
// (bit-identical). Diagonal term is SCALE*x_ii - logS directly.
__global__ __launch_bounds__(256) void minfonce_kernel(
    const float* __restrict__ logits,
    const int*   __restrict__ labels,
    float*       __restrict__ out)
{
    const float SCALE = 7.3890560989306495f;   // e^2 (T = 2.0)
    const int row  = blockIdx.x;
    const int tid  = threadIdx.x;
    const int lane = tid & 63;
    const int wv   = tid >> 6;

    __shared__ float sS[4], sX[4], sM[4], sA[4];

    const float4* rp = reinterpret_cast<const float4*>(logits + (size_t)row * N_DIM);
    const int4*   lp = reinterpret_cast<const int4*>(labels);
    const int     li = labels[row];

    // ---- pass 1: e = exp(scale*x) (|scale*x| < 87, no shift needed);
    //      accumulate S (all), Smask (labels differ), per-k-group max ----
    float m4k[4];
    float s_all = 0.f, s_mask = 0.f;
#pragma unroll
    for (int k = 0; k < 4; ++k) {
        const float4 t  = rp[tid + 256 * k];
        const int4   lb = lp[tid + 256 * k];
        const float ex = __expf(SCALE * t.x);
        const float ey = __expf(SCALE * t.y);
        const float ez = __expf(SCALE * t.z);
        const float ew = __expf(SCALE * t.w);
        s_all  += (ex + ey) + (ez + ew);
        s_mask += ((lb.x != li ? ex : 0.f) + (lb.y != li ? ey : 0.f))
                + ((lb.z != li ? ez : 0.f) + (lb.w != li ? ew : 0.f));
        m4k[k] = fmaxf(fmaxf(ex, ey), fmaxf(ez, ew));
    }
    float emax = fmaxf(fmaxf(m4k[0], m4k[1]), fmaxf(m4k[2], m4k[3]));
#pragma unroll
    for (int off = 1; off < 64; off <<= 1) {
        s_all  += __shfl_xor(s_all, off);
        s_mask += __shfl_xor(s_mask, off);
        emax    = fmaxf(emax, __shfl_xor(emax, off));
    }
    if (lane == 0) { sS[wv] = s_all; sX[wv] = s_mask; sM[wv] = emax; }
    __syncthreads();
    const float S     = (sS[0] + sS[1]) + (sS[2] + sS[3]);
    const float Smask = (sX[0] + sX[1]) + (sX[2] + sX[3]);
    const float Emax  = fmaxf(fmaxf(sM[0], sM[1]), fmaxf(sM[2], sM[3]));
    const float invS  = 1.0f / S;
    const float logS  = __logf(S);
    const float tau   = 1e-3f * S;                       // correction threshold (p > 1e-3)
    // 1 - p_max = (S - Emax)/S, cancellation-free; clamp guards S==Emax rounding.
    const float qmax  = fmaxf(S - Emax, S * 1e-12f) * invS;

    float acc = 0.f;

    // ---- rare-correction scan: elements with p > 1e-3 get exact log(1-p).
    //      Re-load from global (L1/L2 hit) and recompute exp (bit-identical). ----
#pragma unroll
    for (int k = 0; k < 4; ++k) {
        if (m4k[k] > tau) {                   // rare: ~10-30 hits per row total
            const int g = tid + 256 * k;
            const float4 t  = rp[g];
            const int4   lb = lp[g];
            { const float ev = __expf(SCALE * t.x);
              if (ev > tau && lb.x != li) {
                  const float p = ev * invS;
                  const float q = (ev == Emax) ? qmax : (1.0f - p);
                  acc += __logf(q) + p; } }   // exact log1p(-p), minus bulk's -p
            { const float ev = __expf(SCALE * t.y);
              if (ev > tau && lb.y != li) {
                  const float p = ev * invS;
                  const float q = (ev == Emax) ? qmax : (1.0f - p);
                  acc += __logf(q) + p; } }
            { const float ev = __expf(SCALE * t.z);
              if (ev > tau && lb.z != li) {
                  const float p = ev * invS;
                  const float q = (ev == Emax) ? qmax : (1.0f - p);
                  acc += __logf(q) + p; } }
            { const float ev = __expf(SCALE * t.w);
              if (ev > tau && lb.w != li) {
                  const float p = ev * invS;
                  const float q = (ev == Emax) ? qmax : (1.0f - p);
                  acc += __logf(q) + p; } }
        }
    }

    // ---- diagonal term: log p_ii = SCALE*x_ii - logS (one L1-hit load) ----
    if (tid == 0) {
        acc += SCALE * logits[(size_t)row * N_DIM + row] - logS;
    }

#pragma unroll
    for (int off = 1; off < 64; off <<= 1)
        acc += __shfl_xor(acc, off);
    if (lane == 0) sA[wv] = acc;
    __syncthreads();
    if (tid == 0) {
        const float total = (sA[0] + sA[1]) + (sA[2] + sA[3]) - Smask * invS;
        atomicAdd(out, total * (1.0f / N_DIM));
    }
}

extern "C" void kernel_launch(void* const* d_in, const int* in_sizes, int n_in,
                              void* d_out, int out_size, void* d_ws, size_t ws_size,
                              hipStream_t stream) {
    const float* logits = (const float*)d_in[0];
    const int*   labels = (const int*)d_in[1];
    float*       out    = (float*)d_out;

    // d_out is poisoned (0xAA) before every timed launch — zero it ourselves.
    hipMemsetAsync(out, 0, sizeof(float), stream);
    minfonce_kernel<<<N_DIM, 256, 0, stream>>>(logits, labels, out);
}

// Round 7
// 114.554 us; speedup vs baseline: 1.2853x; 1.2056x over previous
//
#include <hip/hip_runtime.h>

#define N_DIM 4096
#define SCALE 7.3890560989306495f   // e^2 (T = 2.0)

// One WAVE per row (4096 waves = 512 blocks x 8 waves), no mid-kernel barriers.
// Lane l owns float4 groups {l + 64*g : g=0..15} of its row (coalesced 1KB/inst).
// Pass 1: e=exp(scale*x) (|scale*x|<87, no shift), accumulate S, Smask, and
// per-group max m16[g]. Intra-wave butterfly reduce. Rare-correction scan
// re-loads hit groups from L1 (bit-identical exp recompute). One atomic/block.
__global__ __launch_bounds__(512, 4) void minfonce_kernel(
    const float* __restrict__ logits,
    const int*   __restrict__ labels,
    float*       __restrict__ out)
{
    const int lane = threadIdx.x & 63;
    const int wv   = threadIdx.x >> 6;
    const int row  = (blockIdx.x << 3) + wv;

    __shared__ float sacc[8];

    const float4* rp = reinterpret_cast<const float4*>(logits + (size_t)row * N_DIM);
    const int4*   lp = reinterpret_cast<const int4*>(labels);
    const int     li = labels[row];

    // ---- pass 1: stream the row, accumulate S / Smask / per-group max ----
    float m16[16];
    float s_all = 0.f, s_mask = 0.f;
#pragma unroll
    for (int g = 0; g < 16; ++g) {
        const float4 t  = rp[lane + 64 * g];
        const int4   lb = lp[lane + 64 * g];
        const float ex = __expf(SCALE * t.x);
        const float ey = __expf(SCALE * t.y);
        const float ez = __expf(SCALE * t.z);
        const float ew = __expf(SCALE * t.w);
        s_all  += (ex + ey) + (ez + ew);
        s_mask += ((lb.x != li ? ex : 0.f) + (lb.y != li ? ey : 0.f))
                + ((lb.z != li ? ez : 0.f) + (lb.w != li ? ew : 0.f));
        m16[g] = fmaxf(fmaxf(ex, ey), fmaxf(ez, ew));
    }
    float emax = m16[0];
#pragma unroll
    for (int g = 1; g < 16; ++g) emax = fmaxf(emax, m16[g]);

    // ---- intra-wave butterfly: all lanes end with row totals ----
#pragma unroll
    for (int off = 1; off < 64; off <<= 1) {
        s_all  += __shfl_xor(s_all, off);
        s_mask += __shfl_xor(s_mask, off);
        emax    = fmaxf(emax, __shfl_xor(emax, off));
    }
    const float S    = s_all;
    const float invS = 1.0f / S;
    const float tau  = 1e-3f * S;                 // correction threshold (p > 1e-3)
    // 1 - p_max = (S - Emax)/S, cancellation-free; clamp guards S==Emax rounding.
    const float qmax = fmaxf(S - emax, S * 1e-12f) * invS;

    // ---- rare-correction scan: groups holding an element with p > 1e-3 ----
    float acc = 0.f;
#pragma unroll
    for (int g = 0; g < 16; ++g) {
        if (m16[g] > tau) {                       // ~1-6 groups active per wave
            const float4 t  = rp[lane + 64 * g];  // L1 hit
            const int4   lb = lp[lane + 64 * g];
            { const float ev = __expf(SCALE * t.x);
              if (ev > tau && lb.x != li) {
                  const float p = ev * invS;
                  const float q = (ev == emax) ? qmax : (1.0f - p);
                  acc += __logf(q) + p; } }       // exact log1p(-p), minus bulk's -p
            { const float ev = __expf(SCALE * t.y);
              if (ev > tau && lb.y != li) {
                  const float p = ev * invS;
                  const float q = (ev == emax) ? qmax : (1.0f - p);
                  acc += __logf(q) + p; } }
            { const float ev = __expf(SCALE * t.z);
              if (ev > tau && lb.z != li) {
                  const float p = ev * invS;
                  const float q = (ev == emax) ? qmax : (1.0f - p);
                  acc += __logf(q) + p; } }
            { const float ev = __expf(SCALE * t.w);
              if (ev > tau && lb.w != li) {
                  const float p = ev * invS;
                  const float q = (ev == emax) ? qmax : (1.0f - p);
                  acc += __logf(q) + p; } }
        }
    }

    // ---- diagonal term: log p_ii = SCALE*x_ii - log S (one L1-hit load) ----
    if (lane == 0)
        acc += SCALE * logits[(size_t)row * N_DIM + row] - __logf(S);

#pragma unroll
    for (int off = 1; off < 64; off <<= 1)
        acc += __shfl_xor(acc, off);

    // ---- one barrier at the very end; one atomic per block ----
    if (lane == 0) sacc[wv] = acc - s_mask * invS;
    __syncthreads();
    if (threadIdx.x == 0) {
        const float total = ((sacc[0] + sacc[1]) + (sacc[2] + sacc[3]))
                          + ((sacc[4] + sacc[5]) + (sacc[6] + sacc[7]));
        atomicAdd(out, total * (1.0f / N_DIM));
    }
}

extern "C" void kernel_launch(void* const* d_in, const int* in_sizes, int n_in,
                              void* d_out, int out_size, void* d_ws, size_t ws_size,
                              hipStream_t stream) {
    const float* logits = (const float*)d_in[0];
    const int*   labels = (const int*)d_in[1];
    float*       out    = (float*)d_out;

    // d_out is poisoned (0xAA) before every timed launch — zero it ourselves.
    hipMemsetAsync(out, 0, sizeof(float), stream);
    minfonce_kernel<<<N_DIM / 8, 512, 0, stream>>>(logits, labels, out);
}